// Round 1
// baseline (1470.297 us; speedup 1.0000x reference)
//
#include <hip/hip_runtime.h>
#include <math.h>

// ---------------------------------------------------------------------------
// GraphNewPolicyNetwork: 2x GCNConv(improved=True) + MLP head + sigmoid +
// gumbel-softmax(hard) straight-through indicator.
// N=100000 nodes, E=1600000 edges, D=H1=H2=64, M1=128, M2=64.
// Outputs: d_out[0:N] = prob (f32), d_out[N:2N] = ind (f32, 0/1).
// ---------------------------------------------------------------------------

// ----------------------------- threefry2x32 --------------------------------
__device__ __forceinline__ unsigned rotl32(unsigned x, int r) {
  return (x << r) | (x >> (32 - r));
}

// JAX threefry2x32 (20 rounds), matches jax/_src/prng.py
__device__ __forceinline__ void threefry2x32(unsigned k0, unsigned k1,
                                             unsigned x0, unsigned x1,
                                             unsigned& o0, unsigned& o1) {
  unsigned ks2 = k0 ^ k1 ^ 0x1BD11BDAu;
#define TF_RND(r) { x0 += x1; x1 = rotl32(x1, (r)); x1 ^= x0; }
  x0 += k0; x1 += k1;
  TF_RND(13) TF_RND(15) TF_RND(26) TF_RND(6)
  x0 += k1; x1 += ks2 + 1u;
  TF_RND(17) TF_RND(29) TF_RND(16) TF_RND(24)
  x0 += ks2; x1 += k0 + 2u;
  TF_RND(13) TF_RND(15) TF_RND(26) TF_RND(6)
  x0 += k0; x1 += k1 + 3u;
  TF_RND(17) TF_RND(29) TF_RND(16) TF_RND(24)
  x0 += k1; x1 += ks2 + 4u;
  TF_RND(13) TF_RND(15) TF_RND(26) TF_RND(6)
  x0 += ks2; x1 += k0 + 5u;
#undef TF_RND
  o0 = x0; o1 = x1;
}

// Partitionable threefry random bits (JAX default since ~0.4.30):
// element with flat index j uses 64-bit counter j -> (hi=0, lo=j), and the
// 32-bit output is out0 ^ out1.
__device__ __forceinline__ unsigned jax_random_bits_u32(unsigned k0, unsigned k1,
                                                        unsigned flat_idx) {
  unsigned a, b;
  threefry2x32(k0, k1, 0u, flat_idx, a, b);
  return a ^ b;
}

// ------------------------------- kernels -----------------------------------

__global__ void count_kernel(const int* __restrict__ dst, float* __restrict__ cnt,
                             int E) {
  int e = blockIdx.x * blockDim.x + threadIdx.x;
  if (e < E) atomicAdd(&cnt[dst[e]], 1.0f);
}

__global__ void dinv_kernel(float* __restrict__ d, int N) {
  int i = blockIdx.x * blockDim.x + threadIdx.x;
  if (i < N) d[i] = 1.0f / sqrtf(d[i] + 2.0f);  // deg = count + 2 (improved)
}

// agg[dst] += xw[src] * dinv[src]*dinv[dst]; one wave (64 lanes) per edge.
__global__ void scatter_kernel(const float* __restrict__ xw,
                               const int* __restrict__ src,
                               const int* __restrict__ dst,
                               const float* __restrict__ dinv,
                               float* __restrict__ agg, int E) {
  int e = (blockIdx.x * blockDim.x + threadIdx.x) >> 6;
  int f = threadIdx.x & 63;
  if (e >= E) return;
  int s = src[e], d = dst[e];
  float nrm = dinv[s] * dinv[d];
  atomicAdd(&agg[(size_t)d * 64 + f], xw[(size_t)s * 64 + f] * nrm);
}

// h = relu(agg + (2*dinv^2)*xw + bias), in place on agg
__global__ void combine_kernel(float* __restrict__ agg, const float* __restrict__ xw,
                               const float* __restrict__ dinv,
                               const float* __restrict__ bias, int N) {
  int idx = blockIdx.x * blockDim.x + threadIdx.x;
  if (idx >= N * 64) return;
  int i = idx >> 6, f = idx & 63;
  float di = dinv[i];
  float t = agg[idx] + (2.0f * di) * di * xw[idx];
  float v = t + bias[f];
  agg[idx] = fmaxf(v, 0.0f);
}

// Y[64-row tile] = X(64 cols) @ W(64 x M)  [+ Y][+ bias][relu]
// flags: 1 = add existing Y (K-split accumulation), 2 = +bias, 4 = relu
template <int M>
__global__ void __launch_bounds__(256)
gemm64_kernel(const float* __restrict__ X, int ldx,
              const float* __restrict__ W,
              const float* __restrict__ bias,
              float* __restrict__ Y, int ldy, int N, int flags) {
  __shared__ float Ws[64 * M];
  __shared__ float Xs[64 * 65];  // +1 pad: bank = (r + k) % 32 -> conflict-free
  const int t = threadIdx.x;
  for (int i = t; i < 64 * M; i += 256) Ws[i] = W[i];
  const int row0 = blockIdx.x * 64;
  for (int i = t; i < 64 * 64; i += 256) {
    int r = i >> 6, c = i & 63;
    int gr = row0 + r;
    Xs[r * 65 + c] = (gr < N) ? X[(size_t)gr * ldx + c] : 0.0f;
  }
  __syncthreads();
  const int r = t & 63;
  const int c0 = (t >> 6) * (M / 4);  // each thread: M/4 contiguous cols
  float acc[M / 4];
#pragma unroll
  for (int j = 0; j < M / 4; ++j) acc[j] = 0.0f;
#pragma unroll 4
  for (int k = 0; k < 64; ++k) {
    float xv = Xs[r * 65 + k];
#pragma unroll
    for (int j = 0; j < M / 4; ++j)
      acc[j] = fmaf(xv, Ws[k * M + c0 + j], acc[j]);
  }
  const int gr = row0 + r;
  if (gr < N) {
#pragma unroll
    for (int j = 0; j < M / 4; ++j) {
      float v = acc[j];
      if (flags & 1) v += Y[(size_t)gr * ldy + c0 + j];
      if (flags & 2) v += bias[c0 + j];
      if (flags & 4) v = fmaxf(v, 0.0f);
      Y[(size_t)gr * ldy + c0 + j] = v;
    }
  }
}

// prob + gumbel straight-through indicator; one wave per node row.
__global__ void head_kernel(const float* __restrict__ zb,
                            const float* __restrict__ Wo,
                            const float* __restrict__ bo,
                            float* __restrict__ out, int N) {
  int row = (blockIdx.x * blockDim.x + threadIdx.x) >> 6;
  int lane = threadIdx.x & 63;
  if (row >= N) return;
  float v = zb[(size_t)row * 64 + lane] * Wo[lane];
#pragma unroll
  for (int off = 32; off > 0; off >>= 1) v += __shfl_xor(v, off, 64);
  if (lane == 0) {
    float w = v + bo[0];
    float p = 1.0f / (1.0f + expf(-w));
    unsigned i = (unsigned)row;
    unsigned b0 = jax_random_bits_u32(0u, 42u, 2u * i);
    unsigned b1 = jax_random_bits_u32(0u, 42u, 2u * i + 1u);
    // jax.random.uniform: bitcast((bits>>9)|0x3f800000)-1, then
    // max(1e-20, f*(1-1e-20)+1e-20)  (== f unless f==0 in fp32)
    float f0 = __uint_as_float((b0 >> 9) | 0x3f800000u) - 1.0f;
    float f1 = __uint_as_float((b1 >> 9) | 0x3f800000u) - 1.0f;
    float u0 = fmaxf(1e-20f, f0 + 1e-20f);
    float u1 = fmaxf(1e-20f, f1 + 1e-20f);
    float g0 = -logf(-logf(u0));
    float g1 = -logf(-logf(u1));
    float a0 = (1.0f - p) + g0;  // logit 0 = 1 - prob
    float a1 = p + g1;           // logit 1 = prob
    float m = fmaxf(a0, a1);
    float e0 = expf(a0 - m), e1 = expf(a1 - m);
    float s = e0 + e1;
    float y0 = e0 / s, y1 = e1 / s;
    float hard1 = (y1 > y0) ? 1.0f : 0.0f;  // argmax, tie -> index 0
    float st1 = (hard1 + y1) - y1;          // straight-through value
    out[row] = p;
    out[N + row] = st1;
  }
}

// ------------------------------- launcher ----------------------------------
extern "C" void kernel_launch(void* const* d_in, const int* in_sizes, int n_in,
                              void* d_out, int out_size, void* d_ws, size_t ws_size,
                              hipStream_t stream) {
  const float* rep = (const float*)d_in[0];
  const int* ei = (const int*)d_in[1];
  const float* W1 = (const float*)d_in[2];
  const float* b1 = (const float*)d_in[3];
  const float* W2 = (const float*)d_in[4];
  const float* b2 = (const float*)d_in[5];
  const float* Wa = (const float*)d_in[6];
  const float* ba = (const float*)d_in[7];
  const float* Wb = (const float*)d_in[8];
  const float* bb = (const float*)d_in[9];
  const float* Wo = (const float*)d_in[10];
  const float* bo = (const float*)d_in[11];
  float* out = (float*)d_out;

  const int N = in_sizes[0] / 64;
  const int E = in_sizes[1] / 2;
  const int* srcI = ei;      // edge_index[0]
  const int* dstI = ei + E;  // edge_index[1]

  float* ws = (float*)d_ws;
  float* bufA = ws;                         // N*64  (xw scratch / zb)
  float* bufB = bufA + (size_t)N * 64;      // N*64  (agg / h)
  float* za = bufB + (size_t)N * 64;        // N*128
  float* dinv = za + (size_t)N * 128;       // N

  const int nb64 = (N + 63) / 64;
  const int nbE = (E + 255) / 256;
  const int nbS = (int)(((size_t)E * 64 + 255) / 256);
  const int nbC = (int)(((size_t)N * 64 + 255) / 256);
  const int nbH = (N + 3) / 4;

  // degree -> dinv
  hipMemsetAsync(dinv, 0, (size_t)N * 4, stream);
  count_kernel<<<nbE, 256, 0, stream>>>(dstI, dinv, E);
  dinv_kernel<<<(N + 255) / 256, 256, 0, stream>>>(dinv, N);

  // ---- GCN layer 1: h1 = relu(Ahat_norm @ (rep@W1) + b1) -> bufB
  gemm64_kernel<64><<<nb64, 256, 0, stream>>>(rep, 64, W1, nullptr, bufA, 64, N, 0);
  hipMemsetAsync(bufB, 0, (size_t)N * 64 * 4, stream);
  scatter_kernel<<<nbS, 256, 0, stream>>>(bufA, srcI, dstI, dinv, bufB, E);
  combine_kernel<<<nbC, 256, 0, stream>>>(bufB, bufA, dinv, b1, N);

  // ---- GCN layer 2: h2 = relu(Ahat_norm @ (h1@W2) + b2) -> bufB
  gemm64_kernel<64><<<nb64, 256, 0, stream>>>(bufB, 64, W2, nullptr, bufA, 64, N, 0);
  hipMemsetAsync(bufB, 0, (size_t)N * 64 * 4, stream);
  scatter_kernel<<<nbS, 256, 0, stream>>>(bufA, srcI, dstI, dinv, bufB, E);
  combine_kernel<<<nbC, 256, 0, stream>>>(bufB, bufA, dinv, b2, N);

  // ---- head: za = relu([rep, h2] @ Wa + ba)   (K=128 split into 2x K=64)
  gemm64_kernel<128><<<nb64, 256, 0, stream>>>(rep, 64, Wa, nullptr, za, 128, N, 0);
  gemm64_kernel<128><<<nb64, 256, 0, stream>>>(bufB, 64, Wa + 64 * 128, ba, za, 128, N,
                                               1 | 2 | 4);
  // zb = relu(za @ Wb + bb) -> bufA   (K=128 split into 2x K=64)
  gemm64_kernel<64><<<nb64, 256, 0, stream>>>(za, 128, Wb, nullptr, bufA, 64, N, 0);
  gemm64_kernel<64><<<nb64, 256, 0, stream>>>(za + 64, 128, Wb + 64 * 64, bb, bufA, 64,
                                              N, 1 | 2 | 4);
  // prob + gumbel hard indicator
  head_kernel<<<nbH, 256, 0, stream>>>(bufA, Wo, bo, out, N);
}

// Round 2
// 634.308 us; speedup vs baseline: 2.3180x; 2.3180x over previous
//
#include <hip/hip_runtime.h>
#include <math.h>

// ---------------------------------------------------------------------------
// GraphNewPolicyNetwork: 2x GCNConv(improved=True) + MLP head + sigmoid +
// gumbel-softmax(hard) straight-through indicator.
// N=100000 nodes, E=1600000 edges, D=H1=H2=64, M1=128, M2=64.
// Outputs: d_out[0:N] = prob (f32), d_out[N:2N] = ind (f32, 0/1).
//
// Round 2: CSR gather aggregation (no float atomics), register-tiled GEMM
// with coalesced float4 epilogue, dinv prescale + self-loop/bias/relu fusion.
// ---------------------------------------------------------------------------

// ----------------------------- threefry2x32 --------------------------------
__device__ __forceinline__ unsigned rotl32(unsigned x, int r) {
  return (x << r) | (x >> (32 - r));
}

// JAX threefry2x32 (20 rounds), matches jax/_src/prng.py
__device__ __forceinline__ void threefry2x32(unsigned k0, unsigned k1,
                                             unsigned x0, unsigned x1,
                                             unsigned& o0, unsigned& o1) {
  unsigned ks2 = k0 ^ k1 ^ 0x1BD11BDAu;
#define TF_RND(r) { x0 += x1; x1 = rotl32(x1, (r)); x1 ^= x0; }
  x0 += k0; x1 += k1;
  TF_RND(13) TF_RND(15) TF_RND(26) TF_RND(6)
  x0 += k1; x1 += ks2 + 1u;
  TF_RND(17) TF_RND(29) TF_RND(16) TF_RND(24)
  x0 += ks2; x1 += k0 + 2u;
  TF_RND(13) TF_RND(15) TF_RND(26) TF_RND(6)
  x0 += k0; x1 += k1 + 3u;
  TF_RND(17) TF_RND(29) TF_RND(16) TF_RND(24)
  x0 += k1; x1 += ks2 + 4u;
  TF_RND(13) TF_RND(15) TF_RND(26) TF_RND(6)
  x0 += ks2; x1 += k0 + 5u;
#undef TF_RND
  o0 = x0; o1 = x1;
}

// Partitionable threefry bits: element flat index j -> counter (0, j),
// 32-bit output = out0 ^ out1.
__device__ __forceinline__ unsigned jax_random_bits_u32(unsigned k0, unsigned k1,
                                                        unsigned flat_idx) {
  unsigned a, b;
  threefry2x32(k0, k1, 0u, flat_idx, a, b);
  return a ^ b;
}

// ------------------------------- CSR build ---------------------------------

__global__ void hist_kernel(const int* __restrict__ dst, int* __restrict__ deg,
                            int E) {
  int e = blockIdx.x * blockDim.x + threadIdx.x;
  if (e < E) atomicAdd(&deg[dst[e]], 1);
}

__global__ void dinv_kernel(const int* __restrict__ deg, float* __restrict__ dinv,
                            int N) {
  int i = blockIdx.x * blockDim.x + threadIdx.x;
  if (i < N) dinv[i] = 1.0f / sqrtf((float)deg[i] + 2.0f);  // improved: +2I
}

// Block b sums deg[b*1024 .. b*1024+1024) -> part[b]
__global__ __launch_bounds__(256) void partial_sum_kernel(
    const int* __restrict__ deg, int* __restrict__ part, int N) {
  __shared__ int sh[256];
  int base = blockIdx.x * 1024;
  int s = 0;
  for (int i = threadIdx.x; i < 1024; i += 256) {
    int g = base + i;
    s += (g < N) ? deg[g] : 0;
  }
  sh[threadIdx.x] = s;
  __syncthreads();
  for (int off = 128; off > 0; off >>= 1) {
    if (threadIdx.x < off) sh[threadIdx.x] += sh[threadIdx.x + off];
    __syncthreads();
  }
  if (threadIdx.x == 0) part[blockIdx.x] = sh[0];
}

// Single block: exclusive scan of part[0..NB) (NB <= 256)
__global__ __launch_bounds__(256) void scan_partials_kernel(int* __restrict__ part,
                                                            int NB) {
  __shared__ int sh[256];
  int t = threadIdx.x;
  int v = (t < NB) ? part[t] : 0;
  sh[t] = v;
  __syncthreads();
  for (int o = 1; o < 256; o <<= 1) {
    int add = (t >= o) ? sh[t - o] : 0;
    __syncthreads();
    sh[t] += add;
    __syncthreads();
  }
  if (t < NB) part[t] = sh[t] - v;  // exclusive
}

// Block b: exclusive scan of its 1024 bins + part[b] -> off, cursor
__global__ __launch_bounds__(256) void write_off_kernel(
    const int* __restrict__ deg, const int* __restrict__ part,
    int* __restrict__ off, int* __restrict__ cursor, int N) {
  __shared__ int sh[256];
  const int t = threadIdx.x;
  const int base = blockIdx.x * 1024 + t * 4;
  int v[4];
  int s = 0;
#pragma unroll
  for (int j = 0; j < 4; ++j) {
    int g = base + j;
    v[j] = (g < N) ? deg[g] : 0;
    s += v[j];
  }
  sh[t] = s;
  __syncthreads();
  for (int o = 1; o < 256; o <<= 1) {
    int add = (t >= o) ? sh[t - o] : 0;
    __syncthreads();
    sh[t] += add;
    __syncthreads();
  }
  int run = part[blockIdx.x] + sh[t] - s;  // exclusive prefix at this chunk
#pragma unroll
  for (int j = 0; j < 4; ++j) {
    int g = base + j;
    if (g < N) {
      off[g] = run;
      cursor[g] = run;
      run += v[j];
      if (g == N - 1) off[N] = run;
    }
  }
}

__global__ void build_csr_kernel(const int* __restrict__ src,
                                 const int* __restrict__ dst,
                                 int* __restrict__ cursor,
                                 int* __restrict__ srcS, int E) {
  int e = blockIdx.x * blockDim.x + threadIdx.x;
  if (e < E) {
    int slot = atomicAdd(&cursor[dst[e]], 1);
    srcS[slot] = src[e];
  }
}

// ---------------------------- aggregation ----------------------------------
// One wave per dst node, lane = feature. xws is dinv-prescaled X@W.
// h[d] = relu(dinv[d]*(sum_{e in CSR[d]} xws[src] + 2*xws[d]) + bias)
__global__ __launch_bounds__(256) void aggregate_kernel(
    const float* __restrict__ xws, const int* __restrict__ srcS,
    const int* __restrict__ off, const float* __restrict__ dinv,
    const float* __restrict__ bias, float* __restrict__ h, int N) {
  int node = (blockIdx.x * blockDim.x + threadIdx.x) >> 6;
  int f = threadIdx.x & 63;
  if (node >= N) return;
  int beg = off[node], end = off[node + 1];
  float a0 = 0.f, a1 = 0.f, a2 = 0.f, a3 = 0.f;
  int e = beg;
  for (; e + 4 <= end; e += 4) {
    int s0 = srcS[e], s1 = srcS[e + 1], s2 = srcS[e + 2], s3 = srcS[e + 3];
    a0 += xws[(size_t)s0 * 64 + f];
    a1 += xws[(size_t)s1 * 64 + f];
    a2 += xws[(size_t)s2 * 64 + f];
    a3 += xws[(size_t)s3 * 64 + f];
  }
  for (; e < end; ++e) a0 += xws[(size_t)srcS[e] * 64 + f];
  float acc = (a0 + a1) + (a2 + a3);
  float di = dinv[node];
  float v = di * (acc + 2.0f * xws[(size_t)node * 64 + f]) + bias[f];
  h[(size_t)node * 64 + f] = fmaxf(v, 0.0f);
}

// ------------------------------- GEMM --------------------------------------
// Y[64-row tile] = X(64 cols) @ W(64 x M), register-tiled 4 rows x (M/16) cols
// per thread, 16x16 thread grid (tx fastest -> coalesced float4 stores).
// flags: 1 = accumulate into Y, 2 = +bias, 4 = relu, 8 = scale by dinv[row]
template <int M>
__global__ __launch_bounds__(256) void gemm64v2_kernel(
    const float* __restrict__ X, int ldx, const float* __restrict__ W,
    const float* __restrict__ bias, const float* __restrict__ dinv,
    float* __restrict__ Y, int ldy, int N, int flags) {
  __shared__ float Ws[64 * M];
  __shared__ float Xs[64 * 64];  // row-major; compute reads are broadcast
  const int t = threadIdx.x;
  // stage W (64 x M), coalesced float4
  {
    const float4* W4 = (const float4*)W;
    float4* Ws4 = (float4*)Ws;
    for (int i = t; i < 16 * M; i += 256) Ws4[i] = W4[i];
  }
  // stage X tile (64 rows x 64 cols), coalesced float4
  const int row0 = blockIdx.x * 64;
  for (int i = t; i < 64 * 16; i += 256) {
    int r = i >> 4, c4 = i & 15;
    int gr = row0 + r;
    float4 v = make_float4(0.f, 0.f, 0.f, 0.f);
    if (gr < N) v = *(const float4*)&X[(size_t)gr * ldx + c4 * 4];
    *(float4*)&Xs[r * 64 + c4 * 4] = v;
  }
  __syncthreads();

  constexpr int MC = M / 16;              // cols per thread (4 or 8)
  const int tx = t & 15, ty = t >> 4;     // 16 x 16 grid
  const int c0 = tx * MC;
  const int r0 = ty * 4;
  float acc[4][MC];
#pragma unroll
  for (int i = 0; i < 4; ++i)
#pragma unroll
    for (int j = 0; j < MC; ++j) acc[i][j] = 0.f;

#pragma unroll 4
  for (int k4 = 0; k4 < 16; ++k4) {
    float4 xv[4];
#pragma unroll
    for (int i = 0; i < 4; ++i)
      xv[i] = *(const float4*)&Xs[(r0 + i) * 64 + k4 * 4];  // broadcast b128
#pragma unroll
    for (int kk = 0; kk < 4; ++kk) {
      float w[MC];
#pragma unroll
      for (int j = 0; j < MC; ++j) w[j] = Ws[(k4 * 4 + kk) * M + c0 + j];
      const float xk[4] = {kk == 0 ? xv[0].x : kk == 1 ? xv[0].y : kk == 2 ? xv[0].z : xv[0].w,
                           kk == 0 ? xv[1].x : kk == 1 ? xv[1].y : kk == 2 ? xv[1].z : xv[1].w,
                           kk == 0 ? xv[2].x : kk == 1 ? xv[2].y : kk == 2 ? xv[2].z : xv[2].w,
                           kk == 0 ? xv[3].x : kk == 1 ? xv[3].y : kk == 2 ? xv[3].z : xv[3].w};
#pragma unroll
      for (int i = 0; i < 4; ++i)
#pragma unroll
        for (int j = 0; j < MC; ++j) acc[i][j] = fmaf(xk[i], w[j], acc[i][j]);
    }
  }

#pragma unroll
  for (int i = 0; i < 4; ++i) {
    int gr = row0 + r0 + i;
    if (gr >= N) continue;
    float sc = (flags & 8) ? dinv[gr] : 1.0f;
    float* yrow = &Y[(size_t)gr * ldy + c0];
#pragma unroll
    for (int jj = 0; jj < MC / 4; ++jj) {
      float4 v = make_float4(acc[i][jj * 4 + 0], acc[i][jj * 4 + 1],
                             acc[i][jj * 4 + 2], acc[i][jj * 4 + 3]);
      if (flags & 1) {
        float4 o = *(const float4*)&yrow[jj * 4];
        v.x += o.x; v.y += o.y; v.z += o.z; v.w += o.w;
      }
      if (flags & 8) { v.x *= sc; v.y *= sc; v.z *= sc; v.w *= sc; }
      if (flags & 2) {
        float4 b = *(const float4*)&bias[c0 + jj * 4];
        v.x += b.x; v.y += b.y; v.z += b.z; v.w += b.w;
      }
      if (flags & 4) {
        v.x = fmaxf(v.x, 0.f); v.y = fmaxf(v.y, 0.f);
        v.z = fmaxf(v.z, 0.f); v.w = fmaxf(v.w, 0.f);
      }
      *(float4*)&yrow[jj * 4] = v;
    }
  }
}

// ------------------------------- head --------------------------------------
// prob + gumbel straight-through indicator; one wave per node row.
__global__ __launch_bounds__(256) void head_kernel(const float* __restrict__ zb,
                                                   const float* __restrict__ Wo,
                                                   const float* __restrict__ bo,
                                                   float* __restrict__ out, int N) {
  int row = (blockIdx.x * blockDim.x + threadIdx.x) >> 6;
  int lane = threadIdx.x & 63;
  if (row >= N) return;
  float v = zb[(size_t)row * 64 + lane] * Wo[lane];
#pragma unroll
  for (int off = 32; off > 0; off >>= 1) v += __shfl_xor(v, off, 64);
  if (lane == 0) {
    float w = v + bo[0];
    float p = 1.0f / (1.0f + expf(-w));
    unsigned i = (unsigned)row;
    unsigned b0 = jax_random_bits_u32(0u, 42u, 2u * i);
    unsigned b1 = jax_random_bits_u32(0u, 42u, 2u * i + 1u);
    float f0 = __uint_as_float((b0 >> 9) | 0x3f800000u) - 1.0f;
    float f1 = __uint_as_float((b1 >> 9) | 0x3f800000u) - 1.0f;
    float u0 = fmaxf(1e-20f, f0 + 1e-20f);
    float u1 = fmaxf(1e-20f, f1 + 1e-20f);
    float g0 = -logf(-logf(u0));
    float g1 = -logf(-logf(u1));
    float a0 = (1.0f - p) + g0;  // logit 0 = 1 - prob
    float a1 = p + g1;           // logit 1 = prob
    float m = fmaxf(a0, a1);
    float e0 = expf(a0 - m), e1 = expf(a1 - m);
    float s = e0 + e1;
    float y0 = e0 / s, y1 = e1 / s;
    float hard1 = (y1 > y0) ? 1.0f : 0.0f;  // argmax, tie -> index 0
    float st1 = (hard1 + y1) - y1;          // straight-through value
    out[row] = p;
    out[N + row] = st1;
  }
}

// ------------------------------- launcher ----------------------------------
extern "C" void kernel_launch(void* const* d_in, const int* in_sizes, int n_in,
                              void* d_out, int out_size, void* d_ws, size_t ws_size,
                              hipStream_t stream) {
  const float* rep = (const float*)d_in[0];
  const int* ei = (const int*)d_in[1];
  const float* W1 = (const float*)d_in[2];
  const float* b1 = (const float*)d_in[3];
  const float* W2 = (const float*)d_in[4];
  const float* b2 = (const float*)d_in[5];
  const float* Wa = (const float*)d_in[6];
  const float* ba = (const float*)d_in[7];
  const float* Wb = (const float*)d_in[8];
  const float* bb = (const float*)d_in[9];
  const float* Wo = (const float*)d_in[10];
  const float* bo = (const float*)d_in[11];
  float* out = (float*)d_out;

  const int N = in_sizes[0] / 64;
  const int E = in_sizes[1] / 2;
  const int* srcI = ei;      // edge_index[0]
  const int* dstI = ei + E;  // edge_index[1]

  float* ws = (float*)d_ws;
  float* bufA = ws;                         // N*64  (xws scratch / zb)
  float* bufB = bufA + (size_t)N * 64;      // N*64  (h1 / h2)
  float* za = bufB + (size_t)N * 64;        // N*128 (CSR ints first, za later)
  float* dinv = za + (size_t)N * 128;       // N

  // CSR arrays live in the za region (dead until the head phase)
  int* deg = (int*)za;
  int* off = deg + N;
  int* cursor = off + N + 1;
  int* part = cursor + N;
  int* srcS = part + 256;

  const int nb64 = (N + 63) / 64;            // GEMM row tiles
  const int nbE = (E + 255) / 256;
  const int nbW = (N + 3) / 4;               // one wave per node
  const int NB = (N + 1023) / 1024;          // scan blocks (<=256)

  // ---- CSR build + dinv
  hipMemsetAsync(deg, 0, (size_t)N * 4, stream);
  hist_kernel<<<nbE, 256, 0, stream>>>(dstI, deg, E);
  dinv_kernel<<<(N + 255) / 256, 256, 0, stream>>>(deg, dinv, N);
  partial_sum_kernel<<<NB, 256, 0, stream>>>(deg, part, N);
  scan_partials_kernel<<<1, 256, 0, stream>>>(part, NB);
  write_off_kernel<<<NB, 256, 0, stream>>>(deg, part, off, cursor, N);
  build_csr_kernel<<<nbE, 256, 0, stream>>>(srcI, dstI, cursor, srcS, E);

  // ---- GCN layer 1: bufA = dinv*(rep@W1); bufB = relu(agg + self + b1)
  gemm64v2_kernel<64><<<nb64, 256, 0, stream>>>(rep, 64, W1, nullptr, dinv, bufA,
                                                64, N, 8);
  aggregate_kernel<<<nbW, 256, 0, stream>>>(bufA, srcS, off, dinv, b1, bufB, N);

  // ---- GCN layer 2
  gemm64v2_kernel<64><<<nb64, 256, 0, stream>>>(bufB, 64, W2, nullptr, dinv, bufA,
                                                64, N, 8);
  aggregate_kernel<<<nbW, 256, 0, stream>>>(bufA, srcS, off, dinv, b2, bufB, N);

  // ---- head: za = relu([rep, h2] @ Wa + ba)   (K=128 split into 2x K=64)
  gemm64v2_kernel<128><<<nb64, 256, 0, stream>>>(rep, 64, Wa, nullptr, nullptr, za,
                                                 128, N, 0);
  gemm64v2_kernel<128><<<nb64, 256, 0, stream>>>(bufB, 64, Wa + 64 * 128, ba,
                                                 nullptr, za, 128, N, 1 | 2 | 4);
  // zb = relu(za @ Wb + bb) -> bufA
  gemm64v2_kernel<64><<<nb64, 256, 0, stream>>>(za, 128, Wb, nullptr, nullptr, bufA,
                                                64, N, 0);
  gemm64v2_kernel<64><<<nb64, 256, 0, stream>>>(za + 64, 128, Wb + 64 * 64, bb,
                                                nullptr, bufA, 64, N, 1 | 2 | 4);
  // prob + gumbel hard indicator
  head_kernel<<<nbW, 256, 0, stream>>>(bufA, Wo, bo, out, N);
}

// Round 3
// 509.439 us; speedup vs baseline: 2.8861x; 1.2451x over previous
//
#include <hip/hip_runtime.h>
#include <math.h>

// ---------------------------------------------------------------------------
// GraphNewPolicyNetwork: 2x GCNConv(improved=True) + MLP head + sigmoid +
// gumbel-softmax(hard) straight-through indicator.
// N=100000 nodes, E=1600000 edges, D=H1=H2=64, M1=128, M2=64.
// Outputs: d_out[0:N] = prob (f32), d_out[N:2N] = ind (f32, 0/1).
//
// Round 3: two-level bucketed CSR build (localized scatter, ~7MB HBM writes
// instead of 105MB), fused head megakernel (za->zb->prob->gumbel in one pass).
// ---------------------------------------------------------------------------

// ----------------------------- threefry2x32 --------------------------------
__device__ __forceinline__ unsigned rotl32(unsigned x, int r) {
  return (x << r) | (x >> (32 - r));
}

// JAX threefry2x32 (20 rounds), matches jax/_src/prng.py
__device__ __forceinline__ void threefry2x32(unsigned k0, unsigned k1,
                                             unsigned x0, unsigned x1,
                                             unsigned& o0, unsigned& o1) {
  unsigned ks2 = k0 ^ k1 ^ 0x1BD11BDAu;
#define TF_RND(r) { x0 += x1; x1 = rotl32(x1, (r)); x1 ^= x0; }
  x0 += k0; x1 += k1;
  TF_RND(13) TF_RND(15) TF_RND(26) TF_RND(6)
  x0 += k1; x1 += ks2 + 1u;
  TF_RND(17) TF_RND(29) TF_RND(16) TF_RND(24)
  x0 += ks2; x1 += k0 + 2u;
  TF_RND(13) TF_RND(15) TF_RND(26) TF_RND(6)
  x0 += k0; x1 += k1 + 3u;
  TF_RND(17) TF_RND(29) TF_RND(16) TF_RND(24)
  x0 += k1; x1 += ks2 + 4u;
  TF_RND(13) TF_RND(15) TF_RND(26) TF_RND(6)
  x0 += ks2; x1 += k0 + 5u;
#undef TF_RND
  o0 = x0; o1 = x1;
}

// Partitionable threefry bits: element flat index j -> counter (0, j),
// 32-bit output = out0 ^ out1.
__device__ __forceinline__ unsigned jax_random_bits_u32(unsigned k0, unsigned k1,
                                                        unsigned flat_idx) {
  unsigned a, b;
  threefry2x32(k0, k1, 0u, flat_idx, a, b);
  return a ^ b;
}

// --------------------------- bucketed CSR build ----------------------------
// Buckets: bucket(d) = d >> shift, NBUCK <= 512.

// Per-block LDS histogram of buckets, merged into global coarse[].
__global__ __launch_bounds__(256) void coarse_hist_kernel(
    const int* __restrict__ dst, int* __restrict__ coarse, int E, int shift) {
  __shared__ int h[512];
  for (int i = threadIdx.x; i < 512; i += 256) h[i] = 0;
  __syncthreads();
  for (int e = blockIdx.x * blockDim.x + threadIdx.x; e < E;
       e += gridDim.x * blockDim.x)
    atomicAdd(&h[dst[e] >> shift], 1);
  __syncthreads();
  for (int i = threadIdx.x; i < 512; i += 256)
    if (h[i]) atomicAdd(&coarse[i], h[i]);
}

// Single block: exclusive scan of coarse -> bbase (bucket ranges) and cbase
// (scatter cursors).
__global__ __launch_bounds__(512) void coarse_scan_kernel(
    const int* __restrict__ coarse, int* __restrict__ bbase,
    int* __restrict__ cbase, int NBUCK) {
  __shared__ int sh[512];
  int t = threadIdx.x;
  int v = (t < NBUCK) ? coarse[t] : 0;
  sh[t] = v;
  __syncthreads();
  for (int o = 1; o < 512; o <<= 1) {
    int a = (t >= o) ? sh[t - o] : 0;
    __syncthreads();
    sh[t] += a;
    __syncthreads();
  }
  if (t < NBUCK) {
    int ex = sh[t] - v;
    bbase[t] = ex;
    cbase[t] = ex;
    if (t == NBUCK - 1) bbase[NBUCK] = sh[t];
  }
}

// Pass A: scatter edges into bucket-contiguous (srcB, dstB). Writes from one
// block land in ~(chunk/NBUCK)-long contiguous runs per bucket.
#define CHUNK 4096
__global__ __launch_bounds__(256) void bucket_scatter_kernel(
    const int* __restrict__ src, const int* __restrict__ dst,
    int* __restrict__ cbase, int* __restrict__ srcB, int* __restrict__ dstB,
    int E, int shift) {
  __shared__ int sS[CHUNK];
  __shared__ int dS[CHUNK];
  __shared__ int cnt[512];
  __shared__ int base[512];
  const int t = threadIdx.x;
  const int e0 = blockIdx.x * CHUNK;
  const int n = min(CHUNK, E - e0);
  for (int i = t; i < 512; i += 256) cnt[i] = 0;
  for (int i = t; i < n; i += 256) {
    sS[i] = src[e0 + i];
    dS[i] = dst[e0 + i];
  }
  __syncthreads();
  for (int i = t; i < n; i += 256) atomicAdd(&cnt[dS[i] >> shift], 1);
  __syncthreads();
  for (int i = t; i < 512; i += 256) {
    int c = cnt[i];
    base[i] = c ? atomicAdd(&cbase[i], c) : 0;
  }
  __syncthreads();
  for (int i = t; i < 512; i += 256) cnt[i] = 0;
  __syncthreads();
  for (int i = t; i < n; i += 256) {
    int b = dS[i] >> shift;
    int r = atomicAdd(&cnt[b], 1);
    int p = base[b] + r;
    srcB[p] = sS[i];
    dstB[p] = dS[i];
  }
}

// deg histogram on bucketed dst: atomics localized to a 4KB window per block.
__global__ __launch_bounds__(256) void hist_local_kernel(
    const int* __restrict__ dstB, const int* __restrict__ bbase,
    int* __restrict__ deg, int S) {
  int b = blockIdx.x / S, s = blockIdx.x - b * S;
  int lo = bbase[b], hi = bbase[b + 1];
  int len = hi - lo;
  int st = lo + (int)((long long)len * s / S);
  int en = lo + (int)((long long)len * (s + 1) / S);
  for (int i = st + threadIdx.x; i < en; i += 256) atomicAdd(&deg[dstB[i]], 1);
}

// Block b sums deg[b*1024 .. +1024) -> part[b]
__global__ __launch_bounds__(256) void partial_sum_kernel(
    const int* __restrict__ deg, int* __restrict__ part, int N) {
  __shared__ int sh[256];
  int base = blockIdx.x * 1024;
  int s = 0;
  for (int i = threadIdx.x; i < 1024; i += 256) {
    int g = base + i;
    s += (g < N) ? deg[g] : 0;
  }
  sh[threadIdx.x] = s;
  __syncthreads();
  for (int off = 128; off > 0; off >>= 1) {
    if (threadIdx.x < off) sh[threadIdx.x] += sh[threadIdx.x + off];
    __syncthreads();
  }
  if (threadIdx.x == 0) part[blockIdx.x] = sh[0];
}

// Single block: exclusive scan of part[0..NB) (NB <= 256)
__global__ __launch_bounds__(256) void scan_partials_kernel(int* __restrict__ part,
                                                            int NB) {
  __shared__ int sh[256];
  int t = threadIdx.x;
  int v = (t < NB) ? part[t] : 0;
  sh[t] = v;
  __syncthreads();
  for (int o = 1; o < 256; o <<= 1) {
    int add = (t >= o) ? sh[t - o] : 0;
    __syncthreads();
    sh[t] += add;
    __syncthreads();
  }
  if (t < NB) part[t] = sh[t] - v;  // exclusive
}

// Block b: exclusive scan of its 1024 deg bins + part[b] -> off, cursor; also
// dinv = rsqrt(deg+2) fused here.
__global__ __launch_bounds__(256) void write_off_kernel(
    const int* __restrict__ deg, const int* __restrict__ part,
    int* __restrict__ off, int* __restrict__ cursor, float* __restrict__ dinv,
    int N) {
  __shared__ int sh[256];
  const int t = threadIdx.x;
  const int base = blockIdx.x * 1024 + t * 4;
  int v[4];
  int s = 0;
#pragma unroll
  for (int j = 0; j < 4; ++j) {
    int g = base + j;
    v[j] = (g < N) ? deg[g] : 0;
    s += v[j];
  }
  sh[t] = s;
  __syncthreads();
  for (int o = 1; o < 256; o <<= 1) {
    int add = (t >= o) ? sh[t - o] : 0;
    __syncthreads();
    sh[t] += add;
    __syncthreads();
  }
  int run = part[blockIdx.x] + sh[t] - s;
#pragma unroll
  for (int j = 0; j < 4; ++j) {
    int g = base + j;
    if (g < N) {
      off[g] = run;
      cursor[g] = run;
      dinv[g] = 1.0f / sqrtf((float)v[j] + 2.0f);
      run += v[j];
      if (g == N - 1) off[N] = run;
    }
  }
}

// Pass B: final CSR scatter over bucketed edges; cursor atomics and srcS
// stores stay inside one bucket's span (~65KB) -> L2-resident.
__global__ __launch_bounds__(256) void build_csr_local_kernel(
    const int* __restrict__ srcB, const int* __restrict__ dstB,
    const int* __restrict__ bbase, int* __restrict__ cursor,
    int* __restrict__ srcS, int S) {
  int b = blockIdx.x / S, s = blockIdx.x - b * S;
  int lo = bbase[b], hi = bbase[b + 1];
  int len = hi - lo;
  int st = lo + (int)((long long)len * s / S);
  int en = lo + (int)((long long)len * (s + 1) / S);
  for (int i = st + threadIdx.x; i < en; i += 256) {
    int pos = atomicAdd(&cursor[dstB[i]], 1);
    srcS[pos] = srcB[i];
  }
}

// ---------------------------- aggregation ----------------------------------
// One wave per dst node, lane = feature. xws is dinv-prescaled X@W.
// h[d] = relu(dinv[d]*(sum_{e in CSR[d]} xws[src] + 2*xws[d]) + bias)
__global__ __launch_bounds__(256) void aggregate_kernel(
    const float* __restrict__ xws, const int* __restrict__ srcS,
    const int* __restrict__ off, const float* __restrict__ dinv,
    const float* __restrict__ bias, float* __restrict__ h, int N) {
  int node = (blockIdx.x * blockDim.x + threadIdx.x) >> 6;
  int f = threadIdx.x & 63;
  if (node >= N) return;
  int beg = off[node], end = off[node + 1];
  float a0 = 0.f, a1 = 0.f, a2 = 0.f, a3 = 0.f;
  int e = beg;
  for (; e + 4 <= end; e += 4) {
    int s0 = srcS[e], s1 = srcS[e + 1], s2 = srcS[e + 2], s3 = srcS[e + 3];
    a0 += xws[(size_t)s0 * 64 + f];
    a1 += xws[(size_t)s1 * 64 + f];
    a2 += xws[(size_t)s2 * 64 + f];
    a3 += xws[(size_t)s3 * 64 + f];
  }
  for (; e < end; ++e) a0 += xws[(size_t)srcS[e] * 64 + f];
  float acc = (a0 + a1) + (a2 + a3);
  float di = dinv[node];
  float v = di * (acc + 2.0f * xws[(size_t)node * 64 + f]) + bias[f];
  h[(size_t)node * 64 + f] = fmaxf(v, 0.0f);
}

// ------------------------------- GEMM --------------------------------------
// Y[64-row tile] = X(64 cols) @ W(64 x 64), register-tiled, float4 epilogue.
// flags: 8 = scale result by dinv[row]
__global__ __launch_bounds__(256) void gemm64v2_kernel(
    const float* __restrict__ X, const float* __restrict__ W,
    const float* __restrict__ dinv, float* __restrict__ Y, int N, int flags) {
  __shared__ float Ws[64 * 64];
  __shared__ float Xs[64 * 64];
  const int t = threadIdx.x;
  {
    const float4* W4 = (const float4*)W;
    float4* Ws4 = (float4*)Ws;
    for (int i = t; i < 16 * 64; i += 256) Ws4[i] = W4[i];
  }
  const int row0 = blockIdx.x * 64;
  for (int i = t; i < 64 * 16; i += 256) {
    int r = i >> 4, c4 = i & 15;
    int gr = row0 + r;
    float4 v = make_float4(0.f, 0.f, 0.f, 0.f);
    if (gr < N) v = *(const float4*)&X[(size_t)gr * 64 + c4 * 4];
    *(float4*)&Xs[r * 64 + c4 * 4] = v;
  }
  __syncthreads();

  const int tx = t & 15, ty = t >> 4;
  const int c0 = tx * 4;
  const int r0 = ty * 4;
  float acc[4][4];
#pragma unroll
  for (int i = 0; i < 4; ++i)
#pragma unroll
    for (int j = 0; j < 4; ++j) acc[i][j] = 0.f;

#pragma unroll 4
  for (int k4 = 0; k4 < 16; ++k4) {
    float4 xv[4];
#pragma unroll
    for (int i = 0; i < 4; ++i)
      xv[i] = *(const float4*)&Xs[(r0 + i) * 64 + k4 * 4];
#pragma unroll
    for (int kk = 0; kk < 4; ++kk) {
      float w[4];
#pragma unroll
      for (int j = 0; j < 4; ++j) w[j] = Ws[(k4 * 4 + kk) * 64 + c0 + j];
      const float xk[4] = {
          kk == 0 ? xv[0].x : kk == 1 ? xv[0].y : kk == 2 ? xv[0].z : xv[0].w,
          kk == 0 ? xv[1].x : kk == 1 ? xv[1].y : kk == 2 ? xv[1].z : xv[1].w,
          kk == 0 ? xv[2].x : kk == 1 ? xv[2].y : kk == 2 ? xv[2].z : xv[2].w,
          kk == 0 ? xv[3].x : kk == 1 ? xv[3].y : kk == 2 ? xv[3].z : xv[3].w};
#pragma unroll
      for (int i = 0; i < 4; ++i)
#pragma unroll
        for (int j = 0; j < 4; ++j) acc[i][j] = fmaf(xk[i], w[j], acc[i][j]);
    }
  }

#pragma unroll
  for (int i = 0; i < 4; ++i) {
    int gr = row0 + r0 + i;
    if (gr >= N) continue;
    float sc = (flags & 8) ? dinv[gr] : 1.0f;
    float4 v = make_float4(acc[i][0], acc[i][1], acc[i][2], acc[i][3]);
    if (flags & 8) { v.x *= sc; v.y *= sc; v.z *= sc; v.w *= sc; }
    *(float4*)&Y[(size_t)gr * 64 + c0] = v;
  }
}

// --------------------------- fused head kernel -----------------------------
// Per 64-row tile: za = relu([rep,h2]@Wa+ba); zb = relu(za@Wb+bb);
// p = sigmoid(zb@Wo+bo); gumbel straight-through. One kernel, no za/zb in HBM.
__global__ __launch_bounds__(256) void head_mega_kernel(
    const float* __restrict__ rep, const float* __restrict__ h2,
    const float* __restrict__ Wa, const float* __restrict__ ba,
    const float* __restrict__ Wb, const float* __restrict__ bb,
    const float* __restrict__ Wo, const float* __restrict__ bo,
    float* __restrict__ out, int N) {
  __shared__ float smem[16384];      // 64 KB
  float* Xs = smem;                  // 64 x 128  ([rep, h2] tile; later zaS)
  float* Wbuf = smem + 8192;         // staging for Wa chunks / Wb / reduction
  const int t = threadIdx.x;
  const int row0 = blockIdx.x * 64;

  // stage [rep, h2] tile (64 x 128), coalesced float4
  for (int i = t; i < 2048; i += 256) {
    int r = i >> 5, c4 = i & 31;
    int gr = row0 + r;
    float4 v = make_float4(0.f, 0.f, 0.f, 0.f);
    if (gr < N)
      v = (c4 < 16) ? *(const float4*)&rep[(size_t)gr * 64 + c4 * 4]
                    : *(const float4*)&h2[(size_t)gr * 64 + (c4 - 16) * 4];
    *(float4*)&Xs[r * 128 + c4 * 4] = v;
  }

  const int tx = t & 15, ty = t >> 4;
  const int c0 = tx * 8;   // za cols (M1=128)
  const int r0 = ty * 4;   // rows
  float za[4][8];
#pragma unroll
  for (int i = 0; i < 4; ++i)
#pragma unroll
    for (int j = 0; j < 8; ++j) za[i][j] = 0.f;

  // za accumulation: K=128 in two 64-row chunks of Wa
  for (int chunk = 0; chunk < 2; ++chunk) {
    __syncthreads();
    const float4* Wa4 = (const float4*)(Wa + chunk * 64 * 128);
    float4* Wb4 = (float4*)Wbuf;
    for (int i = t; i < 2048; i += 256) Wb4[i] = Wa4[i];
    __syncthreads();
    const int kb = chunk * 64;
#pragma unroll 2
    for (int k = 0; k < 64; ++k) {
      float x[4];
#pragma unroll
      for (int i = 0; i < 4; ++i) x[i] = Xs[(r0 + i) * 128 + kb + k];
      float4 w0 = *(const float4*)&Wbuf[k * 128 + c0];
      float4 w1 = *(const float4*)&Wbuf[k * 128 + c0 + 4];
      const float w[8] = {w0.x, w0.y, w0.z, w0.w, w1.x, w1.y, w1.z, w1.w};
#pragma unroll
      for (int i = 0; i < 4; ++i)
#pragma unroll
        for (int j = 0; j < 8; ++j) za[i][j] = fmaf(x[i], w[j], za[i][j]);
    }
  }
  // bias + relu
#pragma unroll
  for (int i = 0; i < 4; ++i)
#pragma unroll
    for (int j = 0; j < 8; ++j)
      za[i][j] = fmaxf(za[i][j] + ba[c0 + j], 0.f);

  // write za into LDS (Xs region is dead now)
  __syncthreads();
  float* zaS = Xs;
#pragma unroll
  for (int i = 0; i < 4; ++i) {
    *(float4*)&zaS[(r0 + i) * 128 + c0] =
        make_float4(za[i][0], za[i][1], za[i][2], za[i][3]);
    *(float4*)&zaS[(r0 + i) * 128 + c0 + 4] =
        make_float4(za[i][4], za[i][5], za[i][6], za[i][7]);
  }
  __syncthreads();
  // stage Wb (128 x 64) into Wbuf
  {
    const float4* Wbg = (const float4*)Wb;
    float4* Wb4 = (float4*)Wbuf;
    for (int i = t; i < 2048; i += 256) Wb4[i] = Wbg[i];
  }
  __syncthreads();

  const int c0b = tx * 4;  // zb cols (M2=64)
  float zb[4][4];
#pragma unroll
  for (int i = 0; i < 4; ++i)
#pragma unroll
    for (int j = 0; j < 4; ++j) zb[i][j] = 0.f;
#pragma unroll 4
  for (int k = 0; k < 128; ++k) {
    float x[4];
#pragma unroll
    for (int i = 0; i < 4; ++i) x[i] = zaS[(r0 + i) * 128 + k];
    float4 w = *(const float4*)&Wbuf[k * 64 + c0b];
    const float wj[4] = {w.x, w.y, w.z, w.w};
#pragma unroll
    for (int i = 0; i < 4; ++i)
#pragma unroll
      for (int j = 0; j < 4; ++j) zb[i][j] = fmaf(x[i], wj[j], zb[i][j]);
  }
  // bias + relu + partial Wo dot
  float part[4];
#pragma unroll
  for (int i = 0; i < 4; ++i) {
    part[i] = 0.f;
#pragma unroll
    for (int j = 0; j < 4; ++j) {
      float v = fmaxf(zb[i][j] + bb[c0b + j], 0.f);
      part[i] = fmaf(v, Wo[c0b + j], part[i]);
    }
  }
  // reduce 16 partials per row via LDS (Wbuf region reused; layout [16][68])
  __syncthreads();
  float* red = Wbuf;
#pragma unroll
  for (int i = 0; i < 4; ++i) red[tx * 68 + r0 + i] = part[i];
  __syncthreads();
  if (t < 64) {
    int gr = row0 + t;
    if (gr < N) {
      float s = 0.f;
#pragma unroll
      for (int u = 0; u < 16; ++u) s += red[u * 68 + t];
      float w = s + bo[0];
      float p = 1.0f / (1.0f + expf(-w));
      unsigned i = (unsigned)gr;
      unsigned bits0 = jax_random_bits_u32(0u, 42u, 2u * i);
      unsigned bits1 = jax_random_bits_u32(0u, 42u, 2u * i + 1u);
      float f0 = __uint_as_float((bits0 >> 9) | 0x3f800000u) - 1.0f;
      float f1 = __uint_as_float((bits1 >> 9) | 0x3f800000u) - 1.0f;
      float u0 = fmaxf(1e-20f, f0 + 1e-20f);
      float u1 = fmaxf(1e-20f, f1 + 1e-20f);
      float g0 = -logf(-logf(u0));
      float g1 = -logf(-logf(u1));
      float a0 = (1.0f - p) + g0;
      float a1 = p + g1;
      float m = fmaxf(a0, a1);
      float e0 = expf(a0 - m), e1 = expf(a1 - m);
      float ssum = e0 + e1;
      float y0 = e0 / ssum, y1 = e1 / ssum;
      float hard1 = (y1 > y0) ? 1.0f : 0.0f;
      float st1 = (hard1 + y1) - y1;
      out[gr] = p;
      out[N + gr] = st1;
    }
  }
}

// ------------------------------- launcher ----------------------------------
extern "C" void kernel_launch(void* const* d_in, const int* in_sizes, int n_in,
                              void* d_out, int out_size, void* d_ws, size_t ws_size,
                              hipStream_t stream) {
  const float* rep = (const float*)d_in[0];
  const int* ei = (const int*)d_in[1];
  const float* W1 = (const float*)d_in[2];
  const float* b1 = (const float*)d_in[3];
  const float* W2 = (const float*)d_in[4];
  const float* b2 = (const float*)d_in[5];
  const float* Wa = (const float*)d_in[6];
  const float* ba = (const float*)d_in[7];
  const float* Wb = (const float*)d_in[8];
  const float* bb = (const float*)d_in[9];
  const float* Wo = (const float*)d_in[10];
  const float* bo = (const float*)d_in[11];
  float* out = (float*)d_out;

  const int N = in_sizes[0] / 64;
  const int E = in_sizes[1] / 2;
  const int* srcI = ei;      // edge_index[0]
  const int* dstI = ei + E;  // edge_index[1]

  // bucket config: NBUCK <= 512
  int shift = 10;
  int NBUCK = (N + (1 << shift) - 1) >> shift;
  while (NBUCK > 512) { shift++; NBUCK = (N + (1 << shift) - 1) >> shift; }

  // workspace layout
  float* ws = (float*)d_ws;
  float* bufA = ws;                          // N*64 (xws / scratch)
  float* bufB = bufA + (size_t)N * 64;       // N*64 (h1 / h2)
  float* dinv = bufB + (size_t)N * 64;       // N
  int* deg = (int*)(dinv + N);               // N
  int* coarse = deg + N;                     // 512
  int* bbase = coarse + 512;                 // 513
  int* cbase = bbase + 513;                  // 512
  int* off = cbase + 512;                    // N+1
  int* cursor = off + N + 1;                 // N
  int* part = cursor + N;                    // 256
  int* srcB = part + 256;                    // E
  int* dstB = srcB + E;                      // E
  int* srcS = dstB + E;                      // E

  const int nb64 = (N + 63) / 64;
  const int nbW = (N + 3) / 4;
  const int NB = (N + 1023) / 1024;          // scan blocks (<=256)
  const int nbA = (E + CHUNK - 1) / CHUNK;
  const int S = 4;                           // sub-blocks per bucket

  // ---- bucketed CSR build + dinv
  hipMemsetAsync(deg, 0, ((size_t)N + 512) * 4, stream);  // deg + coarse
  coarse_hist_kernel<<<256, 256, 0, stream>>>(dstI, coarse, E, shift);
  coarse_scan_kernel<<<1, 512, 0, stream>>>(coarse, bbase, cbase, NBUCK);
  bucket_scatter_kernel<<<nbA, 256, 0, stream>>>(srcI, dstI, cbase, srcB, dstB,
                                                 E, shift);
  hist_local_kernel<<<NBUCK * S, 256, 0, stream>>>(dstB, bbase, deg, S);
  partial_sum_kernel<<<NB, 256, 0, stream>>>(deg, part, N);
  scan_partials_kernel<<<1, 256, 0, stream>>>(part, NB);
  write_off_kernel<<<NB, 256, 0, stream>>>(deg, part, off, cursor, dinv, N);
  build_csr_local_kernel<<<NBUCK * S, 256, 0, stream>>>(srcB, dstB, bbase,
                                                        cursor, srcS, S);

  // ---- GCN layer 1: bufA = dinv*(rep@W1); bufB = relu(agg + self + b1)
  gemm64v2_kernel<<<nb64, 256, 0, stream>>>(rep, W1, dinv, bufA, N, 8);
  aggregate_kernel<<<nbW, 256, 0, stream>>>(bufA, srcS, off, dinv, b1, bufB, N);

  // ---- GCN layer 2
  gemm64v2_kernel<<<nb64, 256, 0, stream>>>(bufB, W2, dinv, bufA, N, 8);
  aggregate_kernel<<<nbW, 256, 0, stream>>>(bufA, srcS, off, dinv, b2, bufB, N);

  // ---- fused head: za -> zb -> prob -> gumbel indicator
  head_mega_kernel<<<nb64, 256, 0, stream>>>(rep, bufB, Wa, ba, Wb, bb, Wo, bo,
                                             out, N);
}

// Round 4
// 410.382 us; speedup vs baseline: 3.5827x; 1.2414x over previous
//
#include <hip/hip_runtime.h>
#include <math.h>

// ---------------------------------------------------------------------------
// GraphNewPolicyNetwork: 2x GCNConv(improved=True) + MLP head + sigmoid +
// gumbel-softmax(hard) straight-through indicator.
// N=100000 nodes, E=1600000 edges, D=H1=H2=64, M1=128, M2=64.
// Outputs: d_out[0:N] = prob (f32), d_out[N:2N] = ind (f32, 0/1).
//
// Round 4: LDS bank-conflict-free head (row pad 132, weights streamed from
// L2) and gemm (pad 68); CSR tail fused into one per-bucket kernel with
// packed (dlocal<<20)|src edges.
// ---------------------------------------------------------------------------

// ----------------------------- threefry2x32 --------------------------------
__device__ __forceinline__ unsigned rotl32(unsigned x, int r) {
  return (x << r) | (x >> (32 - r));
}

// JAX threefry2x32 (20 rounds), matches jax/_src/prng.py
__device__ __forceinline__ void threefry2x32(unsigned k0, unsigned k1,
                                             unsigned x0, unsigned x1,
                                             unsigned& o0, unsigned& o1) {
  unsigned ks2 = k0 ^ k1 ^ 0x1BD11BDAu;
#define TF_RND(r) { x0 += x1; x1 = rotl32(x1, (r)); x1 ^= x0; }
  x0 += k0; x1 += k1;
  TF_RND(13) TF_RND(15) TF_RND(26) TF_RND(6)
  x0 += k1; x1 += ks2 + 1u;
  TF_RND(17) TF_RND(29) TF_RND(16) TF_RND(24)
  x0 += ks2; x1 += k0 + 2u;
  TF_RND(13) TF_RND(15) TF_RND(26) TF_RND(6)
  x0 += k0; x1 += k1 + 3u;
  TF_RND(17) TF_RND(29) TF_RND(16) TF_RND(24)
  x0 += k1; x1 += ks2 + 4u;
  TF_RND(13) TF_RND(15) TF_RND(26) TF_RND(6)
  x0 += ks2; x1 += k0 + 5u;
#undef TF_RND
  o0 = x0; o1 = x1;
}

// Partitionable threefry bits: element flat index j -> counter (0, j),
// 32-bit output = out0 ^ out1.
__device__ __forceinline__ unsigned jax_random_bits_u32(unsigned k0, unsigned k1,
                                                        unsigned flat_idx) {
  unsigned a, b;
  threefry2x32(k0, k1, 0u, flat_idx, a, b);
  return a ^ b;
}

// --------------------------- bucketed CSR build ----------------------------
// bucket(d) = d >> 8  (256 nodes per bucket, NBUCK = ceil(N/256) <= 512).
// Packed edge: (dlocal << 20) | src   (requires src < 2^20, dlocal < 2^12).
#define BSHIFT 8
#define BMASK 255

// Per-block LDS histogram of buckets, merged into global coarse[].
__global__ __launch_bounds__(256) void coarse_hist_kernel(
    const int* __restrict__ dst, int* __restrict__ coarse, int E) {
  __shared__ int h[512];
  for (int i = threadIdx.x; i < 512; i += 256) h[i] = 0;
  __syncthreads();
  for (int e = blockIdx.x * blockDim.x + threadIdx.x; e < E;
       e += gridDim.x * blockDim.x)
    atomicAdd(&h[dst[e] >> BSHIFT], 1);
  __syncthreads();
  for (int i = threadIdx.x; i < 512; i += 256)
    if (h[i]) atomicAdd(&coarse[i], h[i]);
}

// Single block: exclusive scan of coarse -> bbase (bucket ranges) and cbase
// (scatter cursors).
__global__ __launch_bounds__(512) void coarse_scan_kernel(
    const int* __restrict__ coarse, int* __restrict__ bbase,
    int* __restrict__ cbase, int NBUCK) {
  __shared__ int sh[512];
  int t = threadIdx.x;
  int v = (t < NBUCK) ? coarse[t] : 0;
  sh[t] = v;
  __syncthreads();
  for (int o = 1; o < 512; o <<= 1) {
    int a = (t >= o) ? sh[t - o] : 0;
    __syncthreads();
    sh[t] += a;
    __syncthreads();
  }
  if (t < NBUCK) {
    int ex = sh[t] - v;
    bbase[t] = ex;
    cbase[t] = ex;
    if (t == NBUCK - 1) bbase[NBUCK] = sh[t];
  }
}

// Pass A: scatter packed edges into bucket-contiguous pkB.
#define CHUNK 4096
__global__ __launch_bounds__(256) void bucket_scatter_kernel(
    const int* __restrict__ src, const int* __restrict__ dst,
    int* __restrict__ cbase, int* __restrict__ pkB, int E) {
  __shared__ int sS[CHUNK];
  __shared__ int dS[CHUNK];
  __shared__ int cnt[512];
  __shared__ int base[512];
  const int t = threadIdx.x;
  const int e0 = blockIdx.x * CHUNK;
  const int n = min(CHUNK, E - e0);
  for (int i = t; i < 512; i += 256) cnt[i] = 0;
  for (int i = t; i < n; i += 256) {
    sS[i] = src[e0 + i];
    dS[i] = dst[e0 + i];
  }
  __syncthreads();
  for (int i = t; i < n; i += 256) atomicAdd(&cnt[dS[i] >> BSHIFT], 1);
  __syncthreads();
  for (int i = t; i < 512; i += 256) {
    int c = cnt[i];
    base[i] = c ? atomicAdd(&cbase[i], c) : 0;
  }
  __syncthreads();
  for (int i = t; i < 512; i += 256) cnt[i] = 0;
  __syncthreads();
  for (int i = t; i < n; i += 256) {
    int d = dS[i];
    int b = d >> BSHIFT;
    int r = atomicAdd(&cnt[b], 1);
    pkB[base[b] + r] = ((d & BMASK) << 20) | sS[i];
  }
}

// Fused per-bucket finalize: LDS deg-hist -> LDS scan -> off/dinv/cursor ->
// CSR scatter. One block per bucket; all scatter targets within a ~16KB
// window -> L2-resident. Replaces 5 kernels + N-word memset.
__global__ __launch_bounds__(256) void bucket_finalize_kernel(
    const int* __restrict__ pkB, const int* __restrict__ bbase,
    int* __restrict__ off, float* __restrict__ dinv, int* __restrict__ srcS,
    int N) {
  __shared__ int cnt[256];
  __shared__ int sh[256];
  const int t = threadIdx.x;
  const int b = blockIdx.x;
  const int lo = bbase[b], hi = bbase[b + 1];
  cnt[t] = 0;
  __syncthreads();
  for (int i = lo + t; i < hi; i += 256) atomicAdd(&cnt[pkB[i] >> 20], 1);
  __syncthreads();
  const int deg = cnt[t];
  sh[t] = deg;
  __syncthreads();
  for (int o = 1; o < 256; o <<= 1) {
    int a = (t >= o) ? sh[t - o] : 0;
    __syncthreads();
    sh[t] += a;
    __syncthreads();
  }
  const int ex = sh[t] - deg;  // exclusive prefix within bucket
  const int node = (b << BSHIFT) + t;
  if (node < N) {
    off[node] = lo + ex;
    dinv[node] = 1.0f / sqrtf((float)deg + 2.0f);
    if (node == N - 1) off[N] = hi;
  }
  cnt[t] = lo + ex;  // cursor
  __syncthreads();
  for (int i = lo + t; i < hi; i += 256) {
    int u = pkB[i];
    int pos = atomicAdd(&cnt[u >> 20], 1);
    srcS[pos] = u & 0xFFFFF;
  }
}

// ---------------------------- aggregation ----------------------------------
// One wave per dst node, lane = feature. xws is dinv-prescaled X@W.
// h[d] = relu(dinv[d]*(sum_{e in CSR[d]} xws[src] + 2*xws[d]) + bias)
__global__ __launch_bounds__(256) void aggregate_kernel(
    const float* __restrict__ xws, const int* __restrict__ srcS,
    const int* __restrict__ off, const float* __restrict__ dinv,
    const float* __restrict__ bias, float* __restrict__ h, int N) {
  int node = (blockIdx.x * blockDim.x + threadIdx.x) >> 6;
  int f = threadIdx.x & 63;
  if (node >= N) return;
  int beg = off[node], end = off[node + 1];
  float a0 = 0.f, a1 = 0.f, a2 = 0.f, a3 = 0.f;
  int e = beg;
  for (; e + 4 <= end; e += 4) {
    int s0 = srcS[e], s1 = srcS[e + 1], s2 = srcS[e + 2], s3 = srcS[e + 3];
    a0 += xws[(size_t)s0 * 64 + f];
    a1 += xws[(size_t)s1 * 64 + f];
    a2 += xws[(size_t)s2 * 64 + f];
    a3 += xws[(size_t)s3 * 64 + f];
  }
  for (; e < end; ++e) a0 += xws[(size_t)srcS[e] * 64 + f];
  float acc = (a0 + a1) + (a2 + a3);
  float di = dinv[node];
  float v = di * (acc + 2.0f * xws[(size_t)node * 64 + f]) + bias[f];
  h[(size_t)node * 64 + f] = fmaxf(v, 0.0f);
}

// ------------------------------- GEMM --------------------------------------
// Y[64-row tile] = X(64 cols) @ W(64 x 64), register-tiled, float4 epilogue.
// Xs rows padded to 68: ty-group b128 reads land on distinct bank quads.
// flags: 8 = scale result by dinv[row]
__global__ __launch_bounds__(256) void gemm64v2_kernel(
    const float* __restrict__ X, const float* __restrict__ W,
    const float* __restrict__ dinv, float* __restrict__ Y, int N, int flags) {
  __shared__ float Ws[64 * 64];
  __shared__ float Xs[64 * 68];
  const int t = threadIdx.x;
  {
    const float4* W4 = (const float4*)W;
    float4* Ws4 = (float4*)Ws;
    for (int i = t; i < 16 * 64; i += 256) Ws4[i] = W4[i];
  }
  const int row0 = blockIdx.x * 64;
  for (int i = t; i < 64 * 16; i += 256) {
    int r = i >> 4, c4 = i & 15;
    int gr = row0 + r;
    float4 v = make_float4(0.f, 0.f, 0.f, 0.f);
    if (gr < N) v = *(const float4*)&X[(size_t)gr * 64 + c4 * 4];
    *(float4*)&Xs[r * 68 + c4 * 4] = v;
  }
  __syncthreads();

  const int tx = t & 15, ty = t >> 4;
  const int c0 = tx * 4;
  const int r0 = ty * 4;
  float acc[4][4];
#pragma unroll
  for (int i = 0; i < 4; ++i)
#pragma unroll
    for (int j = 0; j < 4; ++j) acc[i][j] = 0.f;

#pragma unroll 4
  for (int k4 = 0; k4 < 16; ++k4) {
    float4 xv[4];
#pragma unroll
    for (int i = 0; i < 4; ++i)
      xv[i] = *(const float4*)&Xs[(r0 + i) * 68 + k4 * 4];
#pragma unroll
    for (int kk = 0; kk < 4; ++kk) {
      float w[4];
#pragma unroll
      for (int j = 0; j < 4; ++j) w[j] = Ws[(k4 * 4 + kk) * 64 + c0 + j];
      const float xk[4] = {
          kk == 0 ? xv[0].x : kk == 1 ? xv[0].y : kk == 2 ? xv[0].z : xv[0].w,
          kk == 0 ? xv[1].x : kk == 1 ? xv[1].y : kk == 2 ? xv[1].z : xv[1].w,
          kk == 0 ? xv[2].x : kk == 1 ? xv[2].y : kk == 2 ? xv[2].z : xv[2].w,
          kk == 0 ? xv[3].x : kk == 1 ? xv[3].y : kk == 2 ? xv[3].z : xv[3].w};
#pragma unroll
      for (int i = 0; i < 4; ++i)
#pragma unroll
        for (int j = 0; j < 4; ++j) acc[i][j] = fmaf(xk[i], w[j], acc[i][j]);
    }
  }

#pragma unroll
  for (int i = 0; i < 4; ++i) {
    int gr = row0 + r0 + i;
    if (gr >= N) continue;
    float sc = (flags & 8) ? dinv[gr] : 1.0f;
    float4 v = make_float4(acc[i][0], acc[i][1], acc[i][2], acc[i][3]);
    if (flags & 8) { v.x *= sc; v.y *= sc; v.z *= sc; v.w *= sc; }
    *(float4*)&Y[(size_t)gr * 64 + c0] = v;
  }
}

// --------------------------- fused head kernel -----------------------------
// Per 64-row tile: za = relu([rep,h2]@Wa+ba); zb = relu(za@Wb+bb);
// p = sigmoid(zb@Wo+bo); gumbel straight-through.
// X/za tile in LDS with row pad 132 (conflict-free scalar reads); Wa/Wb
// streamed from global (L2-resident). LDS = 37.3KB -> 4 blocks/CU.
#define XP 132
__global__ __launch_bounds__(256, 4) void head_mega_kernel(
    const float* __restrict__ rep, const float* __restrict__ h2,
    const float* __restrict__ Wa, const float* __restrict__ ba,
    const float* __restrict__ Wb, const float* __restrict__ bb,
    const float* __restrict__ Wo, const float* __restrict__ bo,
    float* __restrict__ out, int N) {
  __shared__ float smem[64 * XP + 16 * 68];
  float* Xs = smem;                 // 64 x 132 ([rep,h2] tile; later zaS)
  float* red = smem + 64 * XP;      // 16 x 68 reduction area
  const int t = threadIdx.x;
  const int row0 = blockIdx.x * 64;

  // stage [rep, h2] tile (64 x 128 in 132-stride rows), coalesced float4
  for (int i = t; i < 2048; i += 256) {
    int r = i >> 5, c4 = i & 31;
    int gr = row0 + r;
    float4 v = make_float4(0.f, 0.f, 0.f, 0.f);
    if (gr < N)
      v = (c4 < 16) ? *(const float4*)&rep[(size_t)gr * 64 + c4 * 4]
                    : *(const float4*)&h2[(size_t)gr * 64 + (c4 - 16) * 4];
    *(float4*)&Xs[r * XP + c4 * 4] = v;
  }
  __syncthreads();

  const int tx = t & 15, ty = t >> 4;
  const int c0 = tx * 8;   // za cols (M1=128)
  const int r0 = ty * 4;   // rows
  float za[4][8];
#pragma unroll
  for (int i = 0; i < 4; ++i)
#pragma unroll
    for (int j = 0; j < 8; ++j) za[i][j] = 0.f;

  // za: K=128 ascending, Wa streamed from global (L2)
#pragma unroll 2
  for (int k = 0; k < 128; ++k) {
    float x[4];
#pragma unroll
    for (int i = 0; i < 4; ++i) x[i] = Xs[(r0 + i) * XP + k];
    float4 w0 = *(const float4*)&Wa[k * 128 + c0];
    float4 w1 = *(const float4*)&Wa[k * 128 + c0 + 4];
    const float w[8] = {w0.x, w0.y, w0.z, w0.w, w1.x, w1.y, w1.z, w1.w};
#pragma unroll
    for (int i = 0; i < 4; ++i)
#pragma unroll
      for (int j = 0; j < 8; ++j) za[i][j] = fmaf(x[i], w[j], za[i][j]);
  }
  // bias + relu
#pragma unroll
  for (int i = 0; i < 4; ++i)
#pragma unroll
    for (int j = 0; j < 8; ++j)
      za[i][j] = fmaxf(za[i][j] + ba[c0 + j], 0.f);

  // write za into LDS (Xs region is dead now)
  __syncthreads();
  float* zaS = Xs;
#pragma unroll
  for (int i = 0; i < 4; ++i) {
    *(float4*)&zaS[(r0 + i) * XP + c0] =
        make_float4(za[i][0], za[i][1], za[i][2], za[i][3]);
    *(float4*)&zaS[(r0 + i) * XP + c0 + 4] =
        make_float4(za[i][4], za[i][5], za[i][6], za[i][7]);
  }
  __syncthreads();

  const int c0b = tx * 4;  // zb cols (M2=64)
  float zb[4][4];
#pragma unroll
  for (int i = 0; i < 4; ++i)
#pragma unroll
    for (int j = 0; j < 4; ++j) zb[i][j] = 0.f;
#pragma unroll 4
  for (int k = 0; k < 128; ++k) {
    float x[4];
#pragma unroll
    for (int i = 0; i < 4; ++i) x[i] = zaS[(r0 + i) * XP + k];
    float4 w = *(const float4*)&Wb[k * 64 + c0b];
    const float wj[4] = {w.x, w.y, w.z, w.w};
#pragma unroll
    for (int i = 0; i < 4; ++i)
#pragma unroll
      for (int j = 0; j < 4; ++j) zb[i][j] = fmaf(x[i], wj[j], zb[i][j]);
  }
  // bias + relu + partial Wo dot
  float part[4];
#pragma unroll
  for (int i = 0; i < 4; ++i) {
    part[i] = 0.f;
#pragma unroll
    for (int j = 0; j < 4; ++j) {
      float v = fmaxf(zb[i][j] + bb[c0b + j], 0.f);
      part[i] = fmaf(v, Wo[c0b + j], part[i]);
    }
  }
  // reduce 16 partials per row via LDS
  __syncthreads();
#pragma unroll
  for (int i = 0; i < 4; ++i) red[tx * 68 + r0 + i] = part[i];
  __syncthreads();
  if (t < 64) {
    int gr = row0 + t;
    if (gr < N) {
      float s = 0.f;
#pragma unroll
      for (int u = 0; u < 16; ++u) s += red[u * 68 + t];
      float w = s + bo[0];
      float p = 1.0f / (1.0f + expf(-w));
      unsigned i = (unsigned)gr;
      unsigned bits0 = jax_random_bits_u32(0u, 42u, 2u * i);
      unsigned bits1 = jax_random_bits_u32(0u, 42u, 2u * i + 1u);
      float f0 = __uint_as_float((bits0 >> 9) | 0x3f800000u) - 1.0f;
      float f1 = __uint_as_float((bits1 >> 9) | 0x3f800000u) - 1.0f;
      float u0 = fmaxf(1e-20f, f0 + 1e-20f);
      float u1 = fmaxf(1e-20f, f1 + 1e-20f);
      float g0 = -logf(-logf(u0));
      float g1 = -logf(-logf(u1));
      float a0 = (1.0f - p) + g0;
      float a1 = p + g1;
      float m = fmaxf(a0, a1);
      float e0 = expf(a0 - m), e1 = expf(a1 - m);
      float ssum = e0 + e1;
      float y0 = e0 / ssum, y1 = e1 / ssum;
      float hard1 = (y1 > y0) ? 1.0f : 0.0f;
      float st1 = (hard1 + y1) - y1;
      out[gr] = p;
      out[N + gr] = st1;
    }
  }
}

// ------------------------------- launcher ----------------------------------
extern "C" void kernel_launch(void* const* d_in, const int* in_sizes, int n_in,
                              void* d_out, int out_size, void* d_ws, size_t ws_size,
                              hipStream_t stream) {
  const float* rep = (const float*)d_in[0];
  const int* ei = (const int*)d_in[1];
  const float* W1 = (const float*)d_in[2];
  const float* b1 = (const float*)d_in[3];
  const float* W2 = (const float*)d_in[4];
  const float* b2 = (const float*)d_in[5];
  const float* Wa = (const float*)d_in[6];
  const float* ba = (const float*)d_in[7];
  const float* Wb = (const float*)d_in[8];
  const float* bb = (const float*)d_in[9];
  const float* Wo = (const float*)d_in[10];
  const float* bo = (const float*)d_in[11];
  float* out = (float*)d_out;

  const int N = in_sizes[0] / 64;   // < 2^20 (packing requirement)
  const int E = in_sizes[1] / 2;
  const int* srcI = ei;      // edge_index[0]
  const int* dstI = ei + E;  // edge_index[1]

  const int NBUCK = (N + 255) >> BSHIFT;  // <= 512

  // workspace layout
  float* ws = (float*)d_ws;
  float* bufA = ws;                          // N*64 (xws / scratch)
  float* bufB = bufA + (size_t)N * 64;       // N*64 (h1 / h2)
  float* dinv = bufB + (size_t)N * 64;       // N
  int* coarse = (int*)(dinv + N);            // 512
  int* bbase = coarse + 512;                 // 513
  int* cbase = bbase + 513;                  // 512
  int* off = cbase + 512;                    // N+1
  int* pkB = off + N + 1;                    // E (packed bucketed edges)
  int* srcS = pkB + E;                       // E (CSR src list)

  const int nb64 = (N + 63) / 64;
  const int nbW = (N + 3) / 4;
  const int nbA = (E + CHUNK - 1) / CHUNK;

  // ---- bucketed CSR build + dinv (coarse hist -> scan -> scatter -> fused
  //      per-bucket hist/scan/off/dinv/scatter)
  hipMemsetAsync(coarse, 0, 512 * 4, stream);
  coarse_hist_kernel<<<256, 256, 0, stream>>>(dstI, coarse, E);
  coarse_scan_kernel<<<1, 512, 0, stream>>>(coarse, bbase, cbase, NBUCK);
  bucket_scatter_kernel<<<nbA, 256, 0, stream>>>(srcI, dstI, cbase, pkB, E);
  bucket_finalize_kernel<<<NBUCK, 256, 0, stream>>>(pkB, bbase, off, dinv,
                                                    srcS, N);

  // ---- GCN layer 1: bufA = dinv*(rep@W1); bufB = relu(agg + self + b1)
  gemm64v2_kernel<<<nb64, 256, 0, stream>>>(rep, W1, dinv, bufA, N, 8);
  aggregate_kernel<<<nbW, 256, 0, stream>>>(bufA, srcS, off, dinv, b1, bufB, N);

  // ---- GCN layer 2
  gemm64v2_kernel<<<nb64, 256, 0, stream>>>(bufB, W2, dinv, bufA, N, 8);
  aggregate_kernel<<<nbW, 256, 0, stream>>>(bufA, srcS, off, dinv, b2, bufB, N);

  // ---- fused head: za -> zb -> prob -> gumbel indicator
  head_mega_kernel<<<nb64, 256, 0, stream>>>(rep, bufB, Wa, ba, Wb, bb, Wo, bo,
                                             out, N);
}